// Round 1
// baseline (4139.536 us; speedup 1.0000x reference)
//
#include <hip/hip_runtime.h>
#include <float.h>

#define N_Q 8192
#define M_PTS 50000
#define DIM 128
#define KNN 10
#define NCLS 10
#define SPLITS 16
#define PTS_PER_SPLIT (M_PTS / SPLITS)  // 3125

// ---------------------------------------------------------------------------
// Phase 0: y2[j] = ||train_pts[j]||^2.  32 lanes per row, fully coalesced.
// ---------------------------------------------------------------------------
__global__ __launch_bounds__(256) void y2_kernel(const float4* __restrict__ y,
                                                 float* __restrict__ y2) {
    int t = blockIdx.x * 256 + threadIdx.x;   // one float4 per thread; 50000*32 total
    int row = t >> 5;
    int lane32 = t & 31;
    float4 v = y[t];
    float p = v.x * v.x + v.y * v.y + v.z * v.z + v.w * v.w;
    // reduce across the 32 lanes owning this row (xor masks <32 stay in-group)
    #pragma unroll
    for (int off = 16; off > 0; off >>= 1) p += __shfl_xor(p, off, 64);
    if (lane32 == 0) y2[row] = p;
}

// Stable (ties keep earlier entry first) predicated top-K insert.
// Requires caller to have checked s < ts[KNN-1]. All indices compile-time.
__device__ __forceinline__ void topk_insert(float (&ts)[KNN], int (&tl)[KNN],
                                            float s, int lab) {
    #pragma unroll
    for (int p = KNN - 1; p >= 1; --p) {
        bool stay = ts[p] <= s;            // below insertion point: unchanged
        bool from_prev = ts[p - 1] > s;    // above insertion point: shift down
        ts[p] = stay ? ts[p] : (from_prev ? ts[p - 1] : s);
        tl[p] = stay ? tl[p] : (from_prev ? tl[p - 1] : lab);
    }
    if (ts[0] > s) { ts[0] = s; tl[0] = lab; }
}

// ---------------------------------------------------------------------------
// Phase 1: per (query, m-split) partial top-10 of score = y2[j] - 2*dot(x,y_j).
// One thread per query; query row lives in 128 VGPRs; train rows are
// wave-uniform loads (expected to scalarize to s_load -> SGPR FMA operands).
// ---------------------------------------------------------------------------
__global__ __launch_bounds__(256, 2) void knn_partial(
    const float* __restrict__ x, const float* __restrict__ y,
    const int* __restrict__ labels, const float* __restrict__ y2,
    float* __restrict__ pscore, int* __restrict__ plabel) {
    const int q = blockIdx.x * 256 + threadIdx.x;
    const int split = blockIdx.y;
    const int j0 = split * PTS_PER_SPLIT;
    const int j1 = j0 + PTS_PER_SPLIT;

    float4 xq[32];
    const float4* xrow = (const float4*)(x + (size_t)q * DIM);
    #pragma unroll
    for (int i = 0; i < 32; ++i) xq[i] = xrow[i];

    float ts[KNN];
    int   tl[KNN];
    #pragma unroll
    for (int i = 0; i < KNN; ++i) { ts[i] = FLT_MAX; tl[i] = 0; }

    #pragma unroll 2
    for (int j = j0; j < j1; ++j) {
        const float4* yrow = (const float4*)(y + (size_t)j * DIM);  // wave-uniform
        float a0 = 0.f, a1 = 0.f, a2 = 0.f, a3 = 0.f;
        #pragma unroll
        for (int i = 0; i < 32; i += 4) {
            float4 v0 = yrow[i + 0];
            float4 v1 = yrow[i + 1];
            float4 v2 = yrow[i + 2];
            float4 v3 = yrow[i + 3];
            a0 = fmaf(xq[i + 0].x, v0.x, a0);
            a0 = fmaf(xq[i + 0].y, v0.y, a0);
            a0 = fmaf(xq[i + 0].z, v0.z, a0);
            a0 = fmaf(xq[i + 0].w, v0.w, a0);
            a1 = fmaf(xq[i + 1].x, v1.x, a1);
            a1 = fmaf(xq[i + 1].y, v1.y, a1);
            a1 = fmaf(xq[i + 1].z, v1.z, a1);
            a1 = fmaf(xq[i + 1].w, v1.w, a1);
            a2 = fmaf(xq[i + 2].x, v2.x, a2);
            a2 = fmaf(xq[i + 2].y, v2.y, a2);
            a2 = fmaf(xq[i + 2].z, v2.z, a2);
            a2 = fmaf(xq[i + 2].w, v2.w, a2);
            a3 = fmaf(xq[i + 3].x, v3.x, a3);
            a3 = fmaf(xq[i + 3].y, v3.y, a3);
            a3 = fmaf(xq[i + 3].z, v3.z, a3);
            a3 = fmaf(xq[i + 3].w, v3.w, a3);
        }
        float dot = (a0 + a1) + (a2 + a3);
        float s = y2[j] - 2.0f * dot;       // per-query x^2 constant dropped (order-preserving)
        if (s < ts[KNN - 1]) {
            int lab = labels[j];
            topk_insert(ts, tl, s, lab);
        }
    }

    size_t base = ((size_t)q * SPLITS + split) * KNN;
    #pragma unroll
    for (int i = 0; i < KNN; ++i) {
        pscore[base + i] = ts[i];
        plabel[base + i] = tl[i];
    }
}

// ---------------------------------------------------------------------------
// Phase 2: merge 16 sorted partial top-10s per query (stable, so exact ties
// resolve to lowest original index like jax top_k), then majority vote with
// ties going to the LARGEST class label (reference reversed-argmax).
// ---------------------------------------------------------------------------
__global__ __launch_bounds__(256) void knn_final(const float* __restrict__ pscore,
                                                 const int* __restrict__ plabel,
                                                 int* __restrict__ out) {
    const int q = blockIdx.x * 256 + threadIdx.x;
    float ts[KNN];
    int   tl[KNN];
    #pragma unroll
    for (int i = 0; i < KNN; ++i) { ts[i] = FLT_MAX; tl[i] = 0; }

    size_t base = (size_t)q * SPLITS * KNN;
    for (int e = 0; e < SPLITS * KNN; ++e) {
        float s = pscore[base + e];
        if (s < ts[KNN - 1]) {
            int lab = plabel[base + e];
            topk_insert(ts, tl, s, lab);
        }
    }

    int bestc = 0, bestn = -1;
    #pragma unroll
    for (int c = 0; c < NCLS; ++c) {
        int n = 0;
        #pragma unroll
        for (int i = 0; i < KNN; ++i) n += (tl[i] == c) ? 1 : 0;
        if (n >= bestn) { bestn = n; bestc = c; }   // >= : ties -> larger label
    }
    out[q] = bestc;
}

// ---------------------------------------------------------------------------
extern "C" void kernel_launch(void* const* d_in, const int* in_sizes, int n_in,
                              void* d_out, int out_size, void* d_ws, size_t ws_size,
                              hipStream_t stream) {
    const float* x      = (const float*)d_in[0];
    const float* y      = (const float*)d_in[1];
    const int*   labels = (const int*)d_in[2];
    // d_in[3] is k == 10, baked in at compile time.

    char* ws = (char*)d_ws;
    float* y2     = (float*)ws;                                   // 200 KB (pad to 256 KB)
    float* pscore = (float*)(ws + 262144);                        // 8192*16*10*4 = 5.24 MB
    int*   plabel = (int*)(ws + 262144 + (size_t)N_Q * SPLITS * KNN * 4);
    int*   out    = (int*)d_out;

    y2_kernel<<<(M_PTS * 32) / 256, 256, 0, stream>>>((const float4*)y, y2);
    knn_partial<<<dim3(N_Q / 256, SPLITS), 256, 0, stream>>>(x, y, labels, y2,
                                                             pscore, plabel);
    knn_final<<<N_Q / 256, 256, 0, stream>>>(pscore, plabel, out);
}